// Round 10
// baseline (1426.888 us; speedup 1.0000x reference)
//
#include <hip/hip_runtime.h>

#define D_MODEL 768
#define NHEAD   12
#define HDIM    64
#define WINDOW  128
#define D_FF    3072
#define NTOK    32768        // B*S = 4*8192
#define QKVN    (3*D_MODEL)  // 2304

typedef unsigned short u16;
typedef __attribute__((ext_vector_type(8))) short bf16x8;
typedef __attribute__((ext_vector_type(4))) float f32x4;

__device__ __forceinline__ u16 f2bf(float f) {
  unsigned u = __float_as_uint(f);
  return (u16)((u + 0x7FFFu + ((u >> 16) & 1u)) >> 16);
}
__device__ __forceinline__ float bf2f(u16 v) {
  return __uint_as_float(((unsigned)v) << 16);
}

__device__ __forceinline__ void gload16(const void* g, void* l) {
  __builtin_amdgcn_global_load_lds(
      (const __attribute__((address_space(1))) void*)g,
      (__attribute__((address_space(3))) void*)l, 16, 0, 0);
}

// ---------------- fp32 -> bf16 convert (vectorized, grid-stride) ----------
__global__ void cvt_bf16(const float* __restrict__ in, u16* __restrict__ out, int n4) {
  int i = blockIdx.x * blockDim.x + threadIdx.x;
  int stride = gridDim.x * blockDim.x;
  for (; i < n4; i += stride) {
    float4 v = ((const float4*)in)[i];
    ushort4 o;
    o.x = f2bf(v.x); o.y = f2bf(v.y); o.z = f2bf(v.z); o.w = f2bf(v.w);
    ((ushort4*)out)[i] = o;
  }
}

__global__ void concat3(const float* __restrict__ a, const float* __restrict__ b,
                        const float* __restrict__ c, float* __restrict__ o) {
  int i = blockIdx.x * blockDim.x + threadIdx.x;  // 2304 total
  if (i < 768) o[i] = a[i];
  else if (i < 1536) o[i] = b[i - 768];
  else if (i < 2304) o[i] = c[i - 1536];
}

// ---------------- bf16 B^T GEMM, m97 structure --------------------------
// C[M,N] = A[M,K] * B[N,K]^T + bias ; 128x128 tile, BK=32, 4 waves (2x2 of 64x64)
// lda/ldb are row strides of A/B (elements); K is the reduction length.
template<int OUTBF16, int RELU>
__global__ __launch_bounds__(256) void gemm_bt(
    const u16* __restrict__ A, const u16* __restrict__ B,
    const float* __restrict__ bias,
    float* __restrict__ Cf, u16* __restrict__ Cb,
    int M, int N, int K, int lda, int ldb) {
  __shared__ alignas(16) u16 smA[128 * 32];
  __shared__ alignas(16) u16 smB[128 * 32];
  const int nn = N >> 7;
  const int nwg = gridDim.x;
  int bid = blockIdx.x;
  bid = (bid & 7) * (nwg >> 3) + (bid >> 3);  // bijective XCD swizzle (nwg%8==0)
  const int bm = (bid / nn) << 7;
  const int bn = (bid % nn) << 7;
  const int t = threadIdx.x, w = t >> 6, lane = t & 63;
  const int lr = lane & 15;
  const int lk = (lane >> 4) << 3;
  const int wr = (w >> 1) << 6, wc = (w & 1) << 6;
  const int srow = w * 32 + (lane >> 2);
  const int scol = (lane & 3) << 3;
  const u16* Ag = A + (size_t)(bm + srow) * lda + scol;
  const u16* Bg = B + (size_t)(bn + srow) * ldb + scol;
  u16* lA0 = &smA[(w * 32) * 32];
  u16* lA1 = &smA[(w * 32 + 16) * 32];
  u16* lB0 = &smB[(w * 32) * 32];
  u16* lB1 = &smB[(w * 32 + 16) * 32];

  f32x4 acc[4][4] = {};

  for (int kt = 0; kt < K; kt += 32) {
    gload16(Ag + kt, lA0);
    gload16(Ag + (size_t)16 * lda + kt, lA1);
    gload16(Bg + kt, lB0);
    gload16(Bg + (size_t)16 * ldb + kt, lB1);
    __syncthreads();  // drains vmcnt -> tile resident
    bf16x8 af[4], bfr[4];
#pragma unroll
    for (int i = 0; i < 4; i++) af[i] = *(const bf16x8*)&smA[(wr + i * 16 + lr) * 32 + lk];
#pragma unroll
    for (int i = 0; i < 4; i++) bfr[i] = *(const bf16x8*)&smB[(wc + i * 16 + lr) * 32 + lk];
#pragma unroll
    for (int i = 0; i < 4; i++)
#pragma unroll
      for (int j = 0; j < 4; j++)
        acc[i][j] = __builtin_amdgcn_mfma_f32_16x16x32_bf16(af[i], bfr[j], acc[i][j], 0, 0, 0);
    __syncthreads();
  }

  float cbv[4];
#pragma unroll
  for (int j = 0; j < 4; j++) cbv[j] = bias ? bias[bn + wc + j * 16 + lr] : 0.f;
#pragma unroll
  for (int i = 0; i < 4; i++)
#pragma unroll
    for (int j = 0; j < 4; j++)
#pragma unroll
      for (int r = 0; r < 4; r++) {
        int row = bm + wr + i * 16 + ((lane >> 4) << 2) + r;
        int col = bn + wc + j * 16 + lr;
        size_t idx = (size_t)row * N + col;
        float v = acc[i][j][r] + cbv[j];
        if (RELU) v = fmaxf(v, 0.f);
        if (OUTBF16) Cb[idx] = f2bf(v);
        else         Cf[idx] = v;
      }
}

// ---------------- local windowed attention ------------------------------
// one block per (window, head): Q,K XOR-swizzled LDS; V transposed; P via LDS
// qkv/out are pre-offset to the current token chunk; rows are chunk-local.
__global__ __launch_bounds__(256) void attn_local(const u16* __restrict__ qkv,
                                                  float* __restrict__ out) {
  __shared__ alignas(16) u16 smQK[16384];      // Q[128][64] | K[128][64]; later P[128][128]
  __shared__ alignas(16) u16 smVt[64 * 136];   // V^T [d][k], padded stride
  const int h = blockIdx.x % NHEAD;
  const int blk = blockIdx.x / NHEAD;
  const int tok0 = blk * WINDOW;
  const int t = threadIdx.x, w = t >> 6, lane = t & 63;
  const int lr = lane & 15, lk = (lane >> 4) << 3;

#pragma unroll
  for (int i = 0; i < 4; i++) {
    int v = t + i * 256;                 // 0..1023
    int row = v >> 3, c0 = (v & 7) << 3;
    const u16* src = qkv + (size_t)(tok0 + row) * QKVN + h * HDIM + c0;
    bf16x8 q = *(const bf16x8*)src;
    bf16x8 k = *(const bf16x8*)(src + D_MODEL);
    bf16x8 vv = *(const bf16x8*)(src + 2 * D_MODEL);
    int qi = (row * 64 + c0) ^ ((row & 7) << 3);
    *(bf16x8*)&smQK[qi] = q;
    *(bf16x8*)&smQK[8192 + qi] = k;
#pragma unroll
    for (int j = 0; j < 8; j++) smVt[(c0 + j) * 136 + row] = (u16)vv[j];
  }
  __syncthreads();

  const int m0 = w * 32;
  f32x4 s[2][8] = {};
#pragma unroll
  for (int ks = 0; ks < 2; ks++) {
    const int k0 = ks * 32 + lk;
    bf16x8 a[2];
#pragma unroll
    for (int mi = 0; mi < 2; mi++) {
      int r = m0 + mi * 16 + lr;
      a[mi] = *(const bf16x8*)&smQK[(r * 64 + k0) ^ ((r & 7) << 3)];
    }
#pragma unroll
    for (int ni = 0; ni < 8; ni++) {
      int r = ni * 16 + lr;
      bf16x8 b = *(const bf16x8*)&smQK[8192 + ((r * 64 + k0) ^ ((r & 7) << 3))];
#pragma unroll
      for (int mi = 0; mi < 2; mi++)
        s[mi][ni] = __builtin_amdgcn_mfma_f32_16x16x32_bf16(a[mi], b, s[mi][ni], 0, 0, 0);
    }
  }

  const float scale = 0.125f;  // 1/sqrt(64)
  float inv[2][4];
#pragma unroll
  for (int mi = 0; mi < 2; mi++)
#pragma unroll
    for (int r = 0; r < 4; r++) {
      float m = -1e30f;
#pragma unroll
      for (int ni = 0; ni < 8; ni++) m = fmaxf(m, s[mi][ni][r]);
#pragma unroll
      for (int d = 1; d < 16; d <<= 1) m = fmaxf(m, __shfl_xor(m, d));
      float su = 0.f;
#pragma unroll
      for (int ni = 0; ni < 8; ni++) {
        float e = __expf((s[mi][ni][r] - m) * scale);
        s[mi][ni][r] = e;
        su += e;
      }
#pragma unroll
      for (int d = 1; d < 16; d <<= 1) su += __shfl_xor(su, d);
      inv[mi][r] = 1.f / su;
    }
  __syncthreads();  // everyone done reading Q/K before P overwrites them

#pragma unroll
  for (int mi = 0; mi < 2; mi++)
#pragma unroll
    for (int ni = 0; ni < 8; ni++)
#pragma unroll
      for (int r = 0; r < 4; r++) {
        int prow = m0 + mi * 16 + ((lane >> 4) << 2) + r;
        int col = ni * 16 + lr;
        smQK[(prow * 128 + col) ^ ((prow & 7) << 3)] = f2bf(s[mi][ni][r] * inv[mi][r]);
      }
  // each wave reads back only its own 32 P-rows -> no barrier needed

  f32x4 o[2][4] = {};
#pragma unroll
  for (int ks = 0; ks < 4; ks++) {
    const int k0 = ks * 32 + lk;
    bf16x8 pa[2];
#pragma unroll
    for (int mi = 0; mi < 2; mi++) {
      int r = m0 + mi * 16 + lr;
      pa[mi] = *(const bf16x8*)&smQK[(r * 128 + k0) ^ ((r & 7) << 3)];
    }
#pragma unroll
    for (int db = 0; db < 4; db++) {
      int d = db * 16 + lr;
      bf16x8 vb = *(const bf16x8*)&smVt[d * 136 + k0];
#pragma unroll
      for (int mi = 0; mi < 2; mi++)
        o[mi][db] = __builtin_amdgcn_mfma_f32_16x16x32_bf16(pa[mi], vb, o[mi][db], 0, 0, 0);
    }
  }
#pragma unroll
  for (int mi = 0; mi < 2; mi++)
#pragma unroll
    for (int db = 0; db < 4; db++)
#pragma unroll
      for (int r = 0; r < 4; r++) {
        int orow = tok0 + m0 + mi * 16 + ((lane >> 4) << 2) + r;
        int ocol = h * HDIM + db * 16 + lr;
        out[(size_t)orow * D_MODEL + ocol] = o[mi][db][r];
      }
}

// ---------------- fused residual add + LayerNorm ------------------------
// one wave per row (768 cols = 64 lanes x 3 float4)
// ABF: A operand is bf16; OUTBF: emit bf16 to ob, else fp32 to of (in-place ok)
template<int ABF, int OUTBF>
__global__ __launch_bounds__(256) void add_ln(
    const void* __restrict__ Ap, const float* __restrict__ Bv,
    const float* __restrict__ g, const float* __restrict__ be,
    float* __restrict__ of, u16* __restrict__ ob) {
  const int w = threadIdx.x >> 6, lane = threadIdx.x & 63;
  const size_t row = (size_t)blockIdx.x * 4 + w;
  const float4* b4 = (const float4*)(Bv + row * 768);
  float x[12];
  float s = 0.f, s2 = 0.f;
#pragma unroll
  for (int c = 0; c < 3; c++) {
    float4 bv = b4[lane + c * 64];
    float a0, a1, a2, a3;
    if (ABF) {
      ushort4 av = ((const ushort4*)((const u16*)Ap + row * 768))[lane + c * 64];
      a0 = bf2f(av.x); a1 = bf2f(av.y); a2 = bf2f(av.z); a3 = bf2f(av.w);
    } else {
      float4 av = ((const float4*)((const float*)Ap + row * 768))[lane + c * 64];
      a0 = av.x; a1 = av.y; a2 = av.z; a3 = av.w;
    }
    float* xp = &x[c * 4];
    xp[0] = a0 + bv.x; xp[1] = a1 + bv.y; xp[2] = a2 + bv.z; xp[3] = a3 + bv.w;
#pragma unroll
    for (int j = 0; j < 4; j++) { s += xp[j]; s2 += xp[j] * xp[j]; }
  }
#pragma unroll
  for (int d = 1; d < 64; d <<= 1) { s += __shfl_xor(s, d); s2 += __shfl_xor(s2, d); }
  const float mean = s * (1.f / 768.f);
  const float var = s2 * (1.f / 768.f) - mean * mean;
  const float rs = rsqrtf(var + 1e-5f);
  const float4* g4 = (const float4*)g;
  const float4* be4 = (const float4*)be;
#pragma unroll
  for (int c = 0; c < 3; c++) {
    float4 gv = g4[lane + c * 64], bev = be4[lane + c * 64];
    float4 y;
    y.x = (x[c * 4 + 0] - mean) * rs * gv.x + bev.x;
    y.y = (x[c * 4 + 1] - mean) * rs * gv.y + bev.y;
    y.z = (x[c * 4 + 2] - mean) * rs * gv.z + bev.z;
    y.w = (x[c * 4 + 3] - mean) * rs * gv.w + bev.w;
    if (OUTBF) {
      ushort4 o;
      o.x = f2bf(y.x); o.y = f2bf(y.y); o.z = f2bf(y.z); o.w = f2bf(y.w);
      ((ushort4*)(ob + row * 768))[lane + c * 64] = o;
    } else {
      ((float4*)(of + row * 768))[lane + c * 64] = y;
    }
  }
}

// ---------------- launch -------------------------------------------------
extern "C" void kernel_launch(void* const* d_in, const int* in_sizes, int n_in,
                              void* d_out, int out_size, void* d_ws, size_t ws_size,
                              hipStream_t stream) {
  const float* src = (const float*)d_in[0];
  const float* Wq = (const float*)d_in[1];  const float* bq = (const float*)d_in[2];
  const float* Wk = (const float*)d_in[3];  const float* bk = (const float*)d_in[4];
  const float* Wv = (const float*)d_in[5];  const float* bv = (const float*)d_in[6];
  const float* W1 = (const float*)d_in[7];  const float* b1 = (const float*)d_in[8];
  const float* W2 = (const float*)d_in[9];  const float* b2 = (const float*)d_in[10];
  const float* g1 = (const float*)d_in[11]; const float* be1 = (const float*)d_in[12];
  const float* g2 = (const float*)d_in[13]; const float* be2 = (const float*)d_in[14];
  float* outf = (float*)d_out;

  // adaptive token chunk: weights need 12,985,344 B; per-chunk bufs CT*9216 B
  // (srcb CT*1536 + xb CT*1536 + qbuf CT*6144). CT is a pure function of
  // ws_size (constant across calls) -> identical work every call.
  const size_t WFIX = 12985344;
  size_t CT = 4096;
  while (CT > 512 && WFIX + CT * 9216 > ws_size) CT >>= 1;
  if (WFIX + CT * 9216 > ws_size) return;  // ws < 17.7 MB: clean fail, never fault

  char* ws = (char*)d_ws;
  u16*   wqkv = (u16*)(ws + 0);                      // 3,538,944  QKV weights bf16
  u16*   w1b  = (u16*)(ws + 3538944);                // 4,718,592
  u16*   w2b  = (u16*)(ws + 8257536);                // 4,718,592
  float* bqkv = (float*)(ws + 12976128);             //     9,216  concat bias
  u16*   srcb = (u16*)(ws + WFIX);                   // CT*1536    src chunk bf16
  u16*   xb   = (u16*)(ws + WFIX + CT * 1536);       // CT*1536    x chunk bf16
  u16*   qbuf = (u16*)(ws + WFIX + CT * 3072);       // CT*6144    qkv / ffn-h chunk

  // 0. weight prep (once)
  cvt_bf16<<<576, 256, 0, stream>>>(Wq, wqkv, 147456);
  cvt_bf16<<<576, 256, 0, stream>>>(Wk, wqkv + 589824, 147456);
  cvt_bf16<<<576, 256, 0, stream>>>(Wv, wqkv + 1179648, 147456);
  cvt_bf16<<<1024, 256, 0, stream>>>(W1, w1b, 589824);
  cvt_bf16<<<1024, 256, 0, stream>>>(W2, w2b, 589824);
  concat3<<<9, 256, 0, stream>>>(bq, bk, bv, bqkv);

  // per-chunk pipeline: NTOK/CT chunks, each fully local.
  // Swizzle precondition: all gemm grids %8==0 for CT>=512
  // (QKV: (CT/128)*18, FFN1: (CT/128)*24, FFN2: (CT/128)*6; CT/128>=4).
  for (size_t tok0 = 0; tok0 < NTOK; tok0 += CT) {
    const float* src_c = src + tok0 * D_MODEL;
    float*       out_c = outf + tok0 * D_MODEL;
    // 1. src chunk -> bf16
    cvt_bf16<<<768, 256, 0, stream>>>(src_c, srcb, (int)(CT * D_MODEL / 4));
    // 2. QKV projection: [CT,768] x [2304,768]^T -> bf16
    gemm_bt<1, 0><<<(CT / 128) * (QKVN / 128), 256, 0, stream>>>(
        srcb, wqkv, bqkv, nullptr, qbuf, (int)CT, QKVN, D_MODEL, D_MODEL, D_MODEL);
    // 3. local attention -> d_out chunk (fp32 scratch)
    attn_local<<<(CT / WINDOW) * NHEAD, 256, 0, stream>>>(qbuf, out_c);
    // 4. x = LN(src + attn) -> bf16 chunk
    add_ln<0, 1><<<CT / 4, 256, 0, stream>>>(src_c, out_c, g1, be1, nullptr, xb);
    // 5. h = relu(x W1^T + b1) -> bf16 (qbuf reused)
    gemm_bt<1, 1><<<(CT / 128) * (D_FF / 128), 256, 0, stream>>>(
        xb, w1b, b1, nullptr, qbuf, (int)CT, D_FF, D_MODEL, D_MODEL, D_MODEL);
    // 6. ff = h W2^T + b2 -> d_out chunk (attn consumed in step 4)
    gemm_bt<0, 0><<<(CT / 128) * (D_MODEL / 128), 256, 0, stream>>>(
        qbuf, w2b, b2, out_c, nullptr, (int)CT, D_MODEL, D_FF, D_FF, D_FF);
    // 7. out = LN(x + ff), in place on d_out chunk
    add_ln<1, 0><<<CT / 4, 256, 0, stream>>>(xb, out_c, g2, be2, out_c, nullptr);
  }
}

// Round 11
// 876.891 us; speedup vs baseline: 1.6272x; 1.6272x over previous
//
#include <hip/hip_runtime.h>

#define D_MODEL 768
#define NHEAD   12
#define HDIM    64
#define WINDOW  128
#define D_FF    3072
#define NTOK    32768        // B*S = 4*8192
#define QKVN    (3*D_MODEL)  // 2304

typedef unsigned short u16;
typedef __attribute__((ext_vector_type(8))) short bf16x8;
typedef __attribute__((ext_vector_type(4))) float f32x4;

__device__ __forceinline__ u16 f2bf(float f) {
  unsigned u = __float_as_uint(f);
  return (u16)((u + 0x7FFFu + ((u >> 16) & 1u)) >> 16);
}
__device__ __forceinline__ float bf2f(u16 v) {
  return __uint_as_float(((unsigned)v) << 16);
}

__device__ __forceinline__ void gload16(const void* g, void* l) {
  __builtin_amdgcn_global_load_lds(
      (const __attribute__((address_space(1))) void*)g,
      (__attribute__((address_space(3))) void*)l, 16, 0, 0);
}

// ---------------- fp32 -> bf16 convert (vectorized, grid-stride) ----------
__global__ void cvt_bf16(const float* __restrict__ in, u16* __restrict__ out, int n4) {
  int i = blockIdx.x * blockDim.x + threadIdx.x;
  int stride = gridDim.x * blockDim.x;
  for (; i < n4; i += stride) {
    float4 v = ((const float4*)in)[i];
    ushort4 o;
    o.x = f2bf(v.x); o.y = f2bf(v.y); o.z = f2bf(v.z); o.w = f2bf(v.w);
    ((ushort4*)out)[i] = o;
  }
}

__global__ void concat3(const float* __restrict__ a, const float* __restrict__ b,
                        const float* __restrict__ c, float* __restrict__ o) {
  int i = blockIdx.x * blockDim.x + threadIdx.x;  // 2304 total
  if (i < 768) o[i] = a[i];
  else if (i < 1536) o[i] = b[i - 768];
  else if (i < 2304) o[i] = c[i - 1536];
}

// ---------------- bf16 B^T GEMM, m97 structure + 2-phase LDS dbuf --------
// C[M,N] = A[M,K] * B[N,K]^T + bias ; 128x128 tile, BK=32, 4 waves (2x2 of 64x64)
// K-loop is 2-phase pipelined (T3-minimum): stage tile t+1 before computing
// tile t; ONE barrier per iter (drains vmcnt for tile t AND lgkm for the
// previous iter's ds_reads, so the buf^1 overwrite is safe).
template<int OUTBF16, int RELU>
__global__ __launch_bounds__(256) void gemm_bt(
    const u16* __restrict__ A, const u16* __restrict__ B,
    const float* __restrict__ bias,
    float* __restrict__ Cf, u16* __restrict__ Cb,
    int M, int N, int K, int lda, int ldb) {
  __shared__ alignas(16) u16 smA[2][128 * 32];
  __shared__ alignas(16) u16 smB[2][128 * 32];
  const int nn = N >> 7;
  const int nwg = gridDim.x;
  int bid = blockIdx.x;
  bid = (bid & 7) * (nwg >> 3) + (bid >> 3);  // bijective XCD swizzle (nwg%8==0)
  const int bm = (bid / nn) << 7;
  const int bn = (bid % nn) << 7;
  const int t = threadIdx.x, w = t >> 6, lane = t & 63;
  const int lr = lane & 15;
  const int lk = (lane >> 4) << 3;
  const int wr = (w >> 1) << 6, wc = (w & 1) << 6;
  const int srow = w * 32 + (lane >> 2);
  const int scol = (lane & 3) << 3;
  const u16* Ag = A + (size_t)(bm + srow) * lda + scol;
  const u16* Bg = B + (size_t)(bn + srow) * ldb + scol;
  const int lofs0 = (w * 32) * 32;        // wave-uniform LDS base (u16 elems)
  const int lofs1 = (w * 32 + 16) * 32;

  f32x4 acc[4][4] = {};

  // prologue: stage tile 0 into buf 0 (in flight until first barrier)
  gload16(Ag, &smA[0][lofs0]);
  gload16(Ag + (size_t)16 * lda, &smA[0][lofs1]);
  gload16(Bg, &smB[0][lofs0]);
  gload16(Bg + (size_t)16 * ldb, &smB[0][lofs1]);

  int cur = 0;
  for (int kt = 0; kt < K; kt += 32) {
    __syncthreads();  // vmcnt(0): tile[cur] resident; lgkm(0): prev readers done
    if (kt + 32 < K) {  // stage next tile into the other buffer (flies under MFMA)
      gload16(Ag + kt + 32, &smA[cur ^ 1][lofs0]);
      gload16(Ag + (size_t)16 * lda + kt + 32, &smA[cur ^ 1][lofs1]);
      gload16(Bg + kt + 32, &smB[cur ^ 1][lofs0]);
      gload16(Bg + (size_t)16 * ldb + kt + 32, &smB[cur ^ 1][lofs1]);
    }
    bf16x8 af[4], bfr[4];
#pragma unroll
    for (int i = 0; i < 4; i++) af[i] = *(const bf16x8*)&smA[cur][(wr + i * 16 + lr) * 32 + lk];
#pragma unroll
    for (int i = 0; i < 4; i++) bfr[i] = *(const bf16x8*)&smB[cur][(wc + i * 16 + lr) * 32 + lk];
#pragma unroll
    for (int i = 0; i < 4; i++)
#pragma unroll
      for (int j = 0; j < 4; j++)
        acc[i][j] = __builtin_amdgcn_mfma_f32_16x16x32_bf16(af[i], bfr[j], acc[i][j], 0, 0, 0);
    cur ^= 1;
  }

  float cbv[4];
#pragma unroll
  for (int j = 0; j < 4; j++) cbv[j] = bias ? bias[bn + wc + j * 16 + lr] : 0.f;
#pragma unroll
  for (int i = 0; i < 4; i++)
#pragma unroll
    for (int j = 0; j < 4; j++)
#pragma unroll
      for (int r = 0; r < 4; r++) {
        int row = bm + wr + i * 16 + ((lane >> 4) << 2) + r;
        int col = bn + wc + j * 16 + lr;
        size_t idx = (size_t)row * N + col;
        float v = acc[i][j][r] + cbv[j];
        if (RELU) v = fmaxf(v, 0.f);
        if (OUTBF16) Cb[idx] = f2bf(v);
        else         Cf[idx] = v;
      }
}

// ---------------- local windowed attention ------------------------------
// one block per (window, head): Q,K XOR-swizzled LDS; V transposed; P via LDS
// qkv/out are pre-offset to the current token chunk; rows are chunk-local.
__global__ __launch_bounds__(256) void attn_local(const u16* __restrict__ qkv,
                                                  float* __restrict__ out) {
  __shared__ alignas(16) u16 smQK[16384];      // Q[128][64] | K[128][64]; later P[128][128]
  __shared__ alignas(16) u16 smVt[64 * 136];   // V^T [d][k], padded stride
  const int h = blockIdx.x % NHEAD;
  const int blk = blockIdx.x / NHEAD;
  const int tok0 = blk * WINDOW;
  const int t = threadIdx.x, w = t >> 6, lane = t & 63;
  const int lr = lane & 15, lk = (lane >> 4) << 3;

#pragma unroll
  for (int i = 0; i < 4; i++) {
    int v = t + i * 256;                 // 0..1023
    int row = v >> 3, c0 = (v & 7) << 3;
    const u16* src = qkv + (size_t)(tok0 + row) * QKVN + h * HDIM + c0;
    bf16x8 q = *(const bf16x8*)src;
    bf16x8 k = *(const bf16x8*)(src + D_MODEL);
    bf16x8 vv = *(const bf16x8*)(src + 2 * D_MODEL);
    int qi = (row * 64 + c0) ^ ((row & 7) << 3);
    *(bf16x8*)&smQK[qi] = q;
    *(bf16x8*)&smQK[8192 + qi] = k;
#pragma unroll
    for (int j = 0; j < 8; j++) smVt[(c0 + j) * 136 + row] = (u16)vv[j];
  }
  __syncthreads();

  const int m0 = w * 32;
  f32x4 s[2][8] = {};
#pragma unroll
  for (int ks = 0; ks < 2; ks++) {
    const int k0 = ks * 32 + lk;
    bf16x8 a[2];
#pragma unroll
    for (int mi = 0; mi < 2; mi++) {
      int r = m0 + mi * 16 + lr;
      a[mi] = *(const bf16x8*)&smQK[(r * 64 + k0) ^ ((r & 7) << 3)];
    }
#pragma unroll
    for (int ni = 0; ni < 8; ni++) {
      int r = ni * 16 + lr;
      bf16x8 b = *(const bf16x8*)&smQK[8192 + ((r * 64 + k0) ^ ((r & 7) << 3))];
#pragma unroll
      for (int mi = 0; mi < 2; mi++)
        s[mi][ni] = __builtin_amdgcn_mfma_f32_16x16x32_bf16(a[mi], b, s[mi][ni], 0, 0, 0);
    }
  }

  const float scale = 0.125f;  // 1/sqrt(64)
  float inv[2][4];
#pragma unroll
  for (int mi = 0; mi < 2; mi++)
#pragma unroll
    for (int r = 0; r < 4; r++) {
      float m = -1e30f;
#pragma unroll
      for (int ni = 0; ni < 8; ni++) m = fmaxf(m, s[mi][ni][r]);
#pragma unroll
      for (int d = 1; d < 16; d <<= 1) m = fmaxf(m, __shfl_xor(m, d));
      float su = 0.f;
#pragma unroll
      for (int ni = 0; ni < 8; ni++) {
        float e = __expf((s[mi][ni][r] - m) * scale);
        s[mi][ni][r] = e;
        su += e;
      }
#pragma unroll
      for (int d = 1; d < 16; d <<= 1) su += __shfl_xor(su, d);
      inv[mi][r] = 1.f / su;
    }
  __syncthreads();  // everyone done reading Q/K before P overwrites them

#pragma unroll
  for (int mi = 0; mi < 2; mi++)
#pragma unroll
    for (int ni = 0; ni < 8; ni++)
#pragma unroll
      for (int r = 0; r < 4; r++) {
        int prow = m0 + mi * 16 + ((lane >> 4) << 2) + r;
        int col = ni * 16 + lr;
        smQK[(prow * 128 + col) ^ ((prow & 7) << 3)] = f2bf(s[mi][ni][r] * inv[mi][r]);
      }
  // each wave reads back only its own 32 P-rows -> no barrier needed

  f32x4 o[2][4] = {};
#pragma unroll
  for (int ks = 0; ks < 4; ks++) {
    const int k0 = ks * 32 + lk;
    bf16x8 pa[2];
#pragma unroll
    for (int mi = 0; mi < 2; mi++) {
      int r = m0 + mi * 16 + lr;
      pa[mi] = *(const bf16x8*)&smQK[(r * 128 + k0) ^ ((r & 7) << 3)];
    }
#pragma unroll
    for (int db = 0; db < 4; db++) {
      int d = db * 16 + lr;
      bf16x8 vb = *(const bf16x8*)&smVt[d * 136 + k0];
#pragma unroll
      for (int mi = 0; mi < 2; mi++)
        o[mi][db] = __builtin_amdgcn_mfma_f32_16x16x32_bf16(pa[mi], vb, o[mi][db], 0, 0, 0);
    }
  }
#pragma unroll
  for (int mi = 0; mi < 2; mi++)
#pragma unroll
    for (int db = 0; db < 4; db++)
#pragma unroll
      for (int r = 0; r < 4; r++) {
        int orow = tok0 + m0 + mi * 16 + ((lane >> 4) << 2) + r;
        int ocol = h * HDIM + db * 16 + lr;
        out[(size_t)orow * D_MODEL + ocol] = o[mi][db][r];
      }
}

// ---------------- fused residual add + LayerNorm ------------------------
// one wave per row (768 cols = 64 lanes x 3 float4)
// ABF: A operand is bf16; OUTBF: emit bf16 to ob, else fp32 to of (in-place ok)
template<int ABF, int OUTBF>
__global__ __launch_bounds__(256) void add_ln(
    const void* __restrict__ Ap, const float* __restrict__ Bv,
    const float* __restrict__ g, const float* __restrict__ be,
    float* __restrict__ of, u16* __restrict__ ob) {
  const int w = threadIdx.x >> 6, lane = threadIdx.x & 63;
  const size_t row = (size_t)blockIdx.x * 4 + w;
  const float4* b4 = (const float4*)(Bv + row * 768);
  float x[12];
  float s = 0.f, s2 = 0.f;
#pragma unroll
  for (int c = 0; c < 3; c++) {
    float4 bv = b4[lane + c * 64];
    float a0, a1, a2, a3;
    if (ABF) {
      ushort4 av = ((const ushort4*)((const u16*)Ap + row * 768))[lane + c * 64];
      a0 = bf2f(av.x); a1 = bf2f(av.y); a2 = bf2f(av.z); a3 = bf2f(av.w);
    } else {
      float4 av = ((const float4*)((const float*)Ap + row * 768))[lane + c * 64];
      a0 = av.x; a1 = av.y; a2 = av.z; a3 = av.w;
    }
    float* xp = &x[c * 4];
    xp[0] = a0 + bv.x; xp[1] = a1 + bv.y; xp[2] = a2 + bv.z; xp[3] = a3 + bv.w;
#pragma unroll
    for (int j = 0; j < 4; j++) { s += xp[j]; s2 += xp[j] * xp[j]; }
  }
#pragma unroll
  for (int d = 1; d < 64; d <<= 1) { s += __shfl_xor(s, d); s2 += __shfl_xor(s2, d); }
  const float mean = s * (1.f / 768.f);
  const float var = s2 * (1.f / 768.f) - mean * mean;
  const float rs = rsqrtf(var + 1e-5f);
  const float4* g4 = (const float4*)g;
  const float4* be4 = (const float4*)be;
#pragma unroll
  for (int c = 0; c < 3; c++) {
    float4 gv = g4[lane + c * 64], bev = be4[lane + c * 64];
    float4 y;
    y.x = (x[c * 4 + 0] - mean) * rs * gv.x + bev.x;
    y.y = (x[c * 4 + 1] - mean) * rs * gv.y + bev.y;
    y.z = (x[c * 4 + 2] - mean) * rs * gv.z + bev.z;
    y.w = (x[c * 4 + 3] - mean) * rs * gv.w + bev.w;
    if (OUTBF) {
      ushort4 o;
      o.x = f2bf(y.x); o.y = f2bf(y.y); o.z = f2bf(y.z); o.w = f2bf(y.w);
      ((ushort4*)(ob + row * 768))[lane + c * 64] = o;
    } else {
      ((float4*)(of + row * 768))[lane + c * 64] = y;
    }
  }
}

// ---------------- launch -------------------------------------------------
extern "C" void kernel_launch(void* const* d_in, const int* in_sizes, int n_in,
                              void* d_out, int out_size, void* d_ws, size_t ws_size,
                              hipStream_t stream) {
  const float* src = (const float*)d_in[0];
  const float* Wq = (const float*)d_in[1];  const float* bq = (const float*)d_in[2];
  const float* Wk = (const float*)d_in[3];  const float* bk = (const float*)d_in[4];
  const float* Wv = (const float*)d_in[5];  const float* bv = (const float*)d_in[6];
  const float* W1 = (const float*)d_in[7];  const float* b1 = (const float*)d_in[8];
  const float* W2 = (const float*)d_in[9];  const float* b2 = (const float*)d_in[10];
  const float* g1 = (const float*)d_in[11]; const float* be1 = (const float*)d_in[12];
  const float* g2 = (const float*)d_in[13]; const float* be2 = (const float*)d_in[14];
  float* outf = (float*)d_out;

  // adaptive token chunk: weights need 12,985,344 B; per-chunk bufs CT*9216 B
  // (srcb CT*1536 + xb CT*1536 + qbuf CT*6144). CT is a pure function of
  // ws_size (constant across calls) -> identical work every call.
  // R10 measured: CT=4096 fits (ws >= 50.7 MB); try larger first for more TLP.
  const size_t WFIX = 12985344;
  size_t CT = 16384;
  while (CT > 512 && WFIX + CT * 9216 > ws_size) CT >>= 1;
  if (WFIX + CT * 9216 > ws_size) return;  // ws < 17.7 MB: clean fail, never fault

  char* ws = (char*)d_ws;
  u16*   wqkv = (u16*)(ws + 0);                      // 3,538,944  QKV weights bf16
  u16*   w1b  = (u16*)(ws + 3538944);                // 4,718,592
  u16*   w2b  = (u16*)(ws + 8257536);                // 4,718,592
  float* bqkv = (float*)(ws + 12976128);             //     9,216  concat bias
  u16*   srcb = (u16*)(ws + WFIX);                   // CT*1536    src chunk bf16
  u16*   xb   = (u16*)(ws + WFIX + CT * 1536);       // CT*1536    x chunk bf16
  u16*   qbuf = (u16*)(ws + WFIX + CT * 3072);       // CT*6144    qkv / ffn-h chunk

  // 0. weight prep (once)
  cvt_bf16<<<576, 256, 0, stream>>>(Wq, wqkv, 147456);
  cvt_bf16<<<576, 256, 0, stream>>>(Wk, wqkv + 589824, 147456);
  cvt_bf16<<<576, 256, 0, stream>>>(Wv, wqkv + 1179648, 147456);
  cvt_bf16<<<1024, 256, 0, stream>>>(W1, w1b, 589824);
  cvt_bf16<<<1024, 256, 0, stream>>>(W2, w2b, 589824);
  concat3<<<9, 256, 0, stream>>>(bq, bk, bv, bqkv);

  // per-chunk pipeline: NTOK/CT chunks, each fully local.
  // Swizzle precondition: all gemm grids %8==0 for CT>=512
  // (QKV: (CT/128)*18, FFN1: (CT/128)*24, FFN2: (CT/128)*6; CT/128>=4).
  for (size_t tok0 = 0; tok0 < NTOK; tok0 += CT) {
    const float* src_c = src + tok0 * D_MODEL;
    float*       out_c = outf + tok0 * D_MODEL;
    // 1. src chunk -> bf16
    cvt_bf16<<<768, 256, 0, stream>>>(src_c, srcb, (int)(CT * D_MODEL / 4));
    // 2. QKV projection: [CT,768] x [2304,768]^T -> bf16
    gemm_bt<1, 0><<<(CT / 128) * (QKVN / 128), 256, 0, stream>>>(
        srcb, wqkv, bqkv, nullptr, qbuf, (int)CT, QKVN, D_MODEL, D_MODEL, D_MODEL);
    // 3. local attention -> d_out chunk (fp32 scratch)
    attn_local<<<(CT / WINDOW) * NHEAD, 256, 0, stream>>>(qbuf, out_c);
    // 4. x = LN(src + attn) -> bf16 chunk
    add_ln<0, 1><<<CT / 4, 256, 0, stream>>>(src_c, out_c, g1, be1, nullptr, xb);
    // 5. h = relu(x W1^T + b1) -> bf16 (qbuf reused)
    gemm_bt<1, 1><<<(CT / 128) * (D_FF / 128), 256, 0, stream>>>(
        xb, w1b, b1, nullptr, qbuf, (int)CT, D_FF, D_MODEL, D_MODEL, D_MODEL);
    // 6. ff = h W2^T + b2 -> d_out chunk (attn consumed in step 4)
    gemm_bt<0, 0><<<(CT / 128) * (D_MODEL / 128), 256, 0, stream>>>(
        qbuf, w2b, b2, out_c, nullptr, (int)CT, D_MODEL, D_FF, D_FF, D_FF);
    // 7. out = LN(x + ff), in place on d_out chunk
    add_ln<1, 0><<<CT / 4, 256, 0, stream>>>(xb, out_c, g2, be2, out_c, nullptr);
  }
}